// Round 8
// baseline (1231.088 us; speedup 1.0000x reference)
//
#include <hip/hip_runtime.h>

// DHPM fused forward v8 (MI355X / gfx950).
// vs v7: (1) launch_bounds(512,4) -> 2 blocks/CU co-resident (v7's (512,2)
// meant 2 waves/SIMD = 1 block); (2) ONE barrier per nt: one-directional
// exchange g0->g1 of {wc, wsn}, double-buffered by nt parity; g1 owns the
// -wsn*Ydx^2 / -wsn*Ydy^2 partials, folded into res by an end-of-net RMW;
// (3) b1/W2 loads software-pipelined (g0 only); -ax^2,-ay^2 precomputed.

#define HID 200
#define NT 13
#define KT 7
#define BLDK 232           // f16 row stride of W tiles (464 B = 29 granules, odd)
#define WCHUNK 8192
#define NTH 512
#define ELD 68             // exchange row stride (floats; 17 granules, odd)

#define OFF_WU 0           // [13][16][232] f16, 8 KB padded per nt
#define OFF_WV 106496
#define OFF_WF 212992
#define OFF_CU 319488      // [200][8] f32 {ax,ay,at,b0,-ax^2,-ay^2,0,0}
#define OFF_CV 325888
#define OFF_CF 332288      // [200][16] f32 {Wf0 row(12), bf0, pad}

typedef _Float16 f16;
typedef _Float16 f16x2 __attribute__((ext_vector_type(2)));
typedef _Float16 f16x8 __attribute__((ext_vector_type(8)));
typedef float f32x4 __attribute__((ext_vector_type(4)));

#define GLDS16(gp, lp) __builtin_amdgcn_global_load_lds( \
    (const __attribute__((address_space(1))) void*)(gp), \
    (__attribute__((address_space(3))) void*)(lp), 16, 0, 0)

__global__ __launch_bounds__(256) void dhpm_prep(
    const float* __restrict__ Wu1, const float* __restrict__ Wv1, const float* __restrict__ Wf1,
    const float* __restrict__ Wu0, const float* __restrict__ bu0,
    const float* __restrict__ Wv0, const float* __restrict__ bv0,
    const float* __restrict__ Wf0, const float* __restrict__ bf0,
    char* __restrict__ ws)
{
    int id = blockIdx.x * blockDim.x + threadIdx.x;
    const int nW = 3 * NT * 16 * 116;   // 72384
    if (id < nW) {
        const int net = id / (NT*16*116);
        int e = id - net * (NT*16*116);
        const int nt  = e / (16*116);  e -= nt * (16*116);
        const int row = e / 116;
        const int k2  = e - row * 116;
        const int j   = nt*16 + row;
        const int k   = k2*2;
        const float* W = (net == 0) ? Wu1 : (net == 1) ? Wv1 : Wf1;
        f16x2 v; v[0] = (f16)0.f; v[1] = (f16)0.f;
        if (j < HID) {
            if (k     < HID) v[0] = (f16)W[j*HID + k];
            if (k + 1 < HID) v[1] = (f16)W[j*HID + k + 1];
        }
        *(f16x2*)(ws + net*106496 + nt*WCHUNK + row*464 + k2*4) = v;
        return;
    }
    id -= nW;
    if (id < 400) {
        const int net = id / HID;
        const int r   = id - net*HID;
        const float* W0 = net ? Wv0 : Wu0;
        const float* b0 = net ? bv0 : bu0;
        const float ax = W0[r*3+0], ay = W0[r*3+1], at = W0[r*3+2];
        float4 c0, c1;
        c0.x = ax; c0.y = ay; c0.z = at; c0.w = b0[r];
        c1.x = -ax*ax; c1.y = -ay*ay; c1.z = 0.f; c1.w = 0.f;
        char* p = ws + (net ? OFF_CV : OFF_CU) + r*32;
        *(float4*)(p)      = c0;
        *(float4*)(p + 16) = c1;
        return;
    }
    id -= 400;
    if (id < HID) {
        const int i = id;
        float4 c0, c1, c2, c3;
        c0.x = Wf0[i*12+0];  c0.y = Wf0[i*12+1];  c0.z = Wf0[i*12+2];  c0.w = Wf0[i*12+3];
        c1.x = Wf0[i*12+4];  c1.y = Wf0[i*12+5];  c1.z = Wf0[i*12+6];  c1.w = Wf0[i*12+7];
        c2.x = Wf0[i*12+8];  c2.y = Wf0[i*12+9];  c2.z = Wf0[i*12+10]; c2.w = Wf0[i*12+11];
        c3.x = bf0[i]; c3.y = 0.f; c3.z = 0.f; c3.w = 0.f;
        char* p = ws + OFF_CF + i*64;
        *(float4*)(p)      = c0;
        *(float4*)(p + 16) = c1;
        *(float4*)(p + 32) = c2;
        *(float4*)(p + 48) = c3;
    }
}

__device__ __forceinline__ f32x4 mfma16(f16x8 a, f16x8 b, f32x4 c) {
    return __builtin_amdgcn_mfma_f32_16x16x32_f16(a, b, c, 0, 0, 0);
}

// g0 partials: p0=val, p1=+wc*Yxx, p2=+wc*Yyy.
// g1 partials: p0=dx, p1=dy, p2=dt, p3=+wsn*Ydx^2, p4=+wsn*Ydy^2 (subtracted).
__device__ __forceinline__ void run_net(
    const float* __restrict__ inp, const char* __restrict__ ws,
    const int wOff, const int cstOff,
    const float* __restrict__ b1, const float* __restrict__ W2, const float b2s,
    const int cV, const int cXX, const int cYY,
    const int cX, const int cY, const int cT,
    char* __restrict__ Bb0, char* __restrict__ Bb1,
    float* __restrict__ exch, float* __restrict__ res,
    const int gp0, const int lane, const int w, const int q, const int g,
    const int jl, const int klo)
{
    const char* src = ws + wOff;

    // stage nt=0 -> Bb0 (8 waves cover 8 KB), overlaps A'-build
    GLDS16(src + w*1024 + lane*16, Bb0 + w*1024);

    // ---- A' fragments: 3 channels x 7 kt = 84 VGPR ----
    f16x8 aP[3][KT];
    {
        const float4* cst = (const float4*)(ws + cstOff);   // [200][2] float4
        const int pt = gp0 + q*16 + jl;
        const float x = inp[pt*3+0], y = inp[pt*3+1], tt = inp[pt*3+2];
        #pragma unroll
        for (int kt = 0; kt < KT; ++kt) {
            f16x8 f0, f1, f2;
            #pragma unroll
            for (int e = 0; e < 8; ++e) {
                const int i = kt*32 + klo*8 + e;
                const int ic = (i < HID) ? i : 0;   // pad-k rows of B are 0
                const float4 c = cst[ic*2];
                const float z = fmaf(c.x, x, fmaf(c.y, y, fmaf(c.z, tt, c.w)));
                if (g == 0) {
                    const float4 c2 = cst[ic*2+1];  // {-ax^2, -ay^2, -, -}
                    const float s = __sinf(z);
                    f0[e] = (f16)s;
                    f1[e] = (f16)(s * c2.x);
                    f2[e] = (f16)(s * c2.y);
                } else {
                    const float cv = __cosf(z);
                    f0[e] = (f16)(cv * c.x);
                    f1[e] = (f16)(cv * c.y);
                    f2[e] = (f16)(cv * c.z);
                }
            }
            aP[0][kt] = f0; aP[1][kt] = f1; aP[2][kt] = f2;
        }
    }

    float p0a[4] = {0,0,0,0}, p1a[4] = {0,0,0,0}, p2a[4] = {0,0,0,0};
    float p3a[4] = {0,0,0,0}, p4a[4] = {0,0,0,0};

    // exchange: [2 arrays (wc,wsn)][2 parity][16 j][ELD]
    float* EA0 = exch;                // wc  par0
    float* EA1 = exch + 16*ELD;       // wc  par1
    float* EB0 = exch + 32*ELD;       // wsn par0
    float* EB1 = exch + 48*ELD;       // wsn par1

    // software-pipelined b1/W2 (g0 only)
    float bj_n = 0.f, wj_n = 0.f;
    if (g == 0) { bj_n = b1[jl]; wj_n = W2[jl]; }

    __syncthreads();   // Bb0 landed (vmcnt drain); prior-phase LDS dead

    for (int nt = 0; nt < NT; ++nt) {
        const char* Bcur = (nt & 1) ? Bb1 : Bb0;
        char*       Bnxt = (nt & 1) ? Bb0 : Bb1;
        if (nt + 1 < NT)
            GLDS16(src + (nt+1)*WCHUNK + w*1024 + lane*16, Bnxt + w*1024);

        const float bj = bj_n, wj = wj_n;
        if (g == 0 && nt + 1 < NT) {
            const int j2 = (nt+1)*16 + jl;
            bj_n = (j2 < HID) ? b1[j2] : 0.f;
            wj_n = (j2 < HID) ? W2[j2] : 0.f;
        }

        f32x4 acc0 = {0,0,0,0}, acc1 = {0,0,0,0}, acc2 = {0,0,0,0};
        const f16* BH = (const f16*)Bcur;
        #pragma unroll
        for (int kt = 0; kt < KT; ++kt) {
            const f16x8 b = *(const f16x8*)&BH[jl*BLDK + kt*32 + klo*8];
            acc0 = mfma16(aP[0][kt], b, acc0);
            acc1 = mfma16(aP[1][kt], b, acc1);
            acc2 = mfma16(aP[2][kt], b, acc2);
        }

        const int pcol = q*16 + klo*4;
        float* EA = (nt & 1) ? EA1 : EA0;
        float* EB = (nt & 1) ? EB1 : EB0;
        if (g == 0) {
            f32x4 wc4, ws4;
            #pragma unroll
            for (int r = 0; r < 4; ++r) {
                float s1, c1;
                __sincosf(acc0[r] + bj, &s1, &c1);
                wc4[r] = wj * c1;
                ws4[r] = wj * s1;
                p0a[r] += ws4[r];                          // val
                p1a[r] = fmaf(wc4[r], acc1[r], p1a[r]);    // +wc*Yxx
                p2a[r] = fmaf(wc4[r], acc2[r], p2a[r]);    // +wc*Yyy
            }
            *(f32x4*)&EA[jl*ELD + pcol] = wc4;
            *(f32x4*)&EB[jl*ELD + pcol] = ws4;
        }
        __syncthreads();   // exch visible; Bnxt landed; Bcur reads done
        if (g == 1) {
            const f32x4 wc4 = *(const f32x4*)&EA[jl*ELD + pcol];
            const f32x4 ws4 = *(const f32x4*)&EB[jl*ELD + pcol];
            #pragma unroll
            for (int r = 0; r < 4; ++r) {
                p0a[r] = fmaf(wc4[r], acc0[r], p0a[r]);            // dx
                p1a[r] = fmaf(wc4[r], acc1[r], p1a[r]);            // dy
                p2a[r] = fmaf(wc4[r], acc2[r], p2a[r]);            // dt
                p3a[r] = fmaf(ws4[r]*acc0[r], acc0[r], p3a[r]);    // wsn*Ydx^2
                p4a[r] = fmaf(ws4[r]*acc1[r], acc1[r], p4a[r]);    // wsn*Ydy^2
            }
        }
    }

    // butterfly over the 16 j-lanes
    #pragma unroll
    for (int d = 1; d < 16; d <<= 1) {
        #pragma unroll
        for (int r = 0; r < 4; ++r) {
            p0a[r] += __shfl_xor(p0a[r], d);
            p1a[r] += __shfl_xor(p1a[r], d);
            p2a[r] += __shfl_xor(p2a[r], d);
        }
        if (g == 1)
            #pragma unroll
            for (int r = 0; r < 4; ++r) {
                p3a[r] += __shfl_xor(p3a[r], d);
                p4a[r] += __shfl_xor(p4a[r], d);
            }
    }
    const int p0 = q*16 + klo*4;
    if (jl == 0) {
        f32x4 v;
        if (g == 0) {
            #pragma unroll
            for (int r = 0; r < 4; ++r) v[r] = p0a[r] + b2s;
            *(f32x4*)&res[cV*72 + p0] = v;
            #pragma unroll
            for (int r = 0; r < 4; ++r) v[r] = p1a[r];
            *(f32x4*)&res[cXX*72 + p0] = v;
            #pragma unroll
            for (int r = 0; r < 4; ++r) v[r] = p2a[r];
            *(f32x4*)&res[cYY*72 + p0] = v;
        } else {
            #pragma unroll
            for (int r = 0; r < 4; ++r) v[r] = p0a[r];
            *(f32x4*)&res[cX*72 + p0] = v;
            #pragma unroll
            for (int r = 0; r < 4; ++r) v[r] = p1a[r];
            *(f32x4*)&res[cY*72 + p0] = v;
            #pragma unroll
            for (int r = 0; r < 4; ++r) v[r] = p2a[r];
            *(f32x4*)&res[cT*72 + p0] = v;
        }
    }
    __syncthreads();   // g0's xxp/yyp in res before g1's RMW
    if (g == 1 && jl == 0) {
        f32x4 a = *(const f32x4*)&res[cXX*72 + p0];
        f32x4 b = *(const f32x4*)&res[cYY*72 + p0];
        #pragma unroll
        for (int r = 0; r < 4; ++r) { a[r] -= p3a[r]; b[r] -= p4a[r]; }
        *(f32x4*)&res[cXX*72 + p0] = a;
        *(f32x4*)&res[cYY*72 + p0] = b;
    }
}

__global__ __launch_bounds__(NTH, 4) void dhpm_main(
    const float* __restrict__ inp, const char* __restrict__ ws,
    const float* __restrict__ bu1, const float* __restrict__ Wu2, const float* __restrict__ bu2,
    const float* __restrict__ bv1, const float* __restrict__ Wv2, const float* __restrict__ bv2,
    const float* __restrict__ bf1, const float* __restrict__ Wf2, const float* __restrict__ bf2,
    float* __restrict__ out, const int Np)
{
    __shared__ __align__(16) char LDS[41920];
    char*  Bb0  = LDS;                        // 8 KB
    char*  Bb1  = LDS + 8192;                 // 8 KB
    float* exch = (float*)(LDS + 16384);      // 4*16*68*4 = 17408 B
    f16*   Af   = (f16*)LDS;                  // f-net: [64][232] f16 = 29696 B (aliases)
    float* res  = (float*)(LDS + 33792);      // [14][72] f32 = 4032 B
    float* pfb  = (float*)(LDS + 37824);      // [8][2][64] f32 = 4096 B

    const int t = threadIdx.x;
    const int lane = t & 63;
    const int w = __builtin_amdgcn_readfirstlane(t >> 6);
    const int q = w & 3, g = w >> 2;
    const int jl = lane & 15, klo = lane >> 4;
    const int gp0 = blockIdx.x * 64;

    run_net(inp, ws, OFF_WU, OFF_CU, bu1, Wu2, bu2[0], 0, 5, 7, 4, 6, 2,
            Bb0, Bb1, exch, res, gp0, lane, w, q, g, jl, klo);
    run_net(inp, ws, OFF_WV, OFF_CV, bv1, Wv2, bv2[0], 1, 9, 11, 8, 10, 3,
            Bb0, Bb1, exch, res, gp0, lane, w, q, g, jl, klo);

    __syncthreads();   // res cols 0..11 final (incl. RMW); Bb/exch region free

    // ======================= f-net =======================
    // j-split: wave w owns nt = w (all) and nt = w+8 (w<5). Wf1 fragments
    // register-resident from L2; shared A_f tile in LDS.
    const int nown = (w < 5) ? 2 : 1;
    f16x8 bF[2][KT];
    #pragma unroll
    for (int ont = 0; ont < 2; ++ont)
        if (ont < nown) {
            const int nt = w + ont*8;
            #pragma unroll
            for (int kt = 0; kt < KT; ++kt)
                bF[ont][kt] = *(const f16x8*)(ws + OFF_WF + nt*WCHUNK
                                              + jl*464 + kt*64 + klo*16);
        }

    if (w < 4) {   // waves 0..3 build A_f for pts w*16+jl
        const int p = w*16 + jl;
        float fv[12];
        #pragma unroll
        for (int k = 0; k < 12; ++k) fv[k] = res[k*72 + p];
        const float4* cf = (const float4*)(ws + OFF_CF);
        #pragma unroll
        for (int kt = 0; kt < KT; ++kt) {
            f16x8 f;
            #pragma unroll
            for (int e = 0; e < 8; ++e) {
                const int i = kt*32 + klo*8 + e;
                const int ic = (i < HID) ? i : 0;
                const float4 c0 = cf[ic*4+0];
                const float4 c1 = cf[ic*4+1];
                const float4 c2 = cf[ic*4+2];
                const float4 c3 = cf[ic*4+3];
                float z = c3.x;
                z = fmaf(c0.x, fv[0], z);  z = fmaf(c0.y, fv[1], z);
                z = fmaf(c0.z, fv[2], z);  z = fmaf(c0.w, fv[3], z);
                z = fmaf(c1.x, fv[4], z);  z = fmaf(c1.y, fv[5], z);
                z = fmaf(c1.z, fv[6], z);  z = fmaf(c1.w, fv[7], z);
                z = fmaf(c2.x, fv[8], z);  z = fmaf(c2.y, fv[9], z);
                z = fmaf(c2.z, fv[10], z); z = fmaf(c2.w, fv[11], z);
                f[e] = (f16)__sinf(z);
            }
            *(f16x8*)((char*)Af + p*464 + kt*64 + klo*16) = f;
        }
    }
    __syncthreads();   // A_f complete

    f32x4 accF[2][4];
    #pragma unroll
    for (int ont = 0; ont < 2; ++ont)
        #pragma unroll
        for (int mt = 0; mt < 4; ++mt) { f32x4 z = {0,0,0,0}; accF[ont][mt] = z; }

    #pragma unroll
    for (int kt = 0; kt < KT; ++kt)
        #pragma unroll
        for (int mt = 0; mt < 4; ++mt) {
            const f16x8 a = *(const f16x8*)((const char*)Af
                                + (mt*16 + jl)*464 + kt*64 + klo*16);
            #pragma unroll
            for (int ont = 0; ont < 2; ++ont)
                if (ont < nown)
                    accF[ont][mt] = mfma16(a, bF[ont][kt], accF[ont][mt]);
        }

    float pf0[4][4], pf1[4][4];
    #pragma unroll
    for (int mt = 0; mt < 4; ++mt)
        #pragma unroll
        for (int r = 0; r < 4; ++r) { pf0[mt][r] = 0.f; pf1[mt][r] = 0.f; }

    #pragma unroll
    for (int ont = 0; ont < 2; ++ont)
        if (ont < nown) {
            const int j = (w + ont*8)*16 + jl;
            const float bj = (j < HID) ? bf1[j] : 0.f;
            const float wa = (j < HID) ? Wf2[j] : 0.f;
            const float wb = (j < HID) ? Wf2[HID + j] : 0.f;
            #pragma unroll
            for (int mt = 0; mt < 4; ++mt)
                #pragma unroll
                for (int r = 0; r < 4; ++r) {
                    const float h = __sinf(accF[ont][mt][r] + bj);
                    pf0[mt][r] = fmaf(wa, h, pf0[mt][r]);
                    pf1[mt][r] = fmaf(wb, h, pf1[mt][r]);
                }
        }

    #pragma unroll
    for (int d = 1; d < 16; d <<= 1)
        #pragma unroll
        for (int mt = 0; mt < 4; ++mt)
            #pragma unroll
            for (int r = 0; r < 4; ++r) {
                pf0[mt][r] += __shfl_xor(pf0[mt][r], d);
                pf1[mt][r] += __shfl_xor(pf1[mt][r], d);
            }
    if (jl == 0) {
        #pragma unroll
        for (int mt = 0; mt < 4; ++mt) {
            f32x4 v0, v1;
            #pragma unroll
            for (int r = 0; r < 4; ++r) { v0[r] = pf0[mt][r]; v1[r] = pf1[mt][r]; }
            *(f32x4*)&pfb[w*128 + 0*64 + mt*16 + klo*4] = v0;
            *(f32x4*)&pfb[w*128 + 1*64 + mt*16 + klo*4] = v1;
        }
    }
    __syncthreads();
    if (t < 128) {
        const int pt = t & 63, ch = t >> 6;
        float s = bf2[ch];
        #pragma unroll
        for (int ww = 0; ww < 8; ++ww) s += pfb[ww*128 + ch*64 + pt];
        res[(12 + ch)*72 + pt] = s;
    }
    __syncthreads();

    // coalesced final store
    for (int e = t; e < 14*64; e += NTH) {
        const int c = e >> 6, p = e & 63;
        out[(size_t)c*Np + gp0 + p] = res[c*72 + p];
    }
}

extern "C" void kernel_launch(void* const* d_in, const int* in_sizes, int n_in,
                              void* d_out, int out_size, void* d_ws, size_t ws_size,
                              hipStream_t stream) {
    const float* inp = (const float*)d_in[0];
    const float* Wu0 = (const float*)d_in[1];  const float* bu0 = (const float*)d_in[2];
    const float* Wu1 = (const float*)d_in[3];  const float* bu1 = (const float*)d_in[4];
    const float* Wu2 = (const float*)d_in[5];  const float* bu2 = (const float*)d_in[6];
    const float* Wv0 = (const float*)d_in[7];  const float* bv0 = (const float*)d_in[8];
    const float* Wv1 = (const float*)d_in[9];  const float* bv1 = (const float*)d_in[10];
    const float* Wv2 = (const float*)d_in[11]; const float* bv2 = (const float*)d_in[12];
    const float* Wf0 = (const float*)d_in[13]; const float* bf0 = (const float*)d_in[14];
    const float* Wf1 = (const float*)d_in[15]; const float* bf1 = (const float*)d_in[16];
    const float* Wf2 = (const float*)d_in[17]; const float* bf2 = (const float*)d_in[18];
    float* out = (float*)d_out;
    char* ws = (char*)d_ws;   // ~345 KB used

    const int Np = in_sizes[0] / 3;  // 262144

    const int nTot = 3*NT*16*116 + 400 + HID;  // 72984
    dhpm_prep<<<(nTot + 255) / 256, 256, 0, stream>>>(
        Wu1, Wv1, Wf1, Wu0, bu0, Wv0, bv0, Wf0, bf0, ws);
    dhpm_main<<<Np / 64, NTH, 0, stream>>>(
        inp, ws, bu1, Wu2, bu2, bv1, Wv2, bv2, bf1, Wf2, bf2, out, Np);
}

// Round 9
// 1095.403 us; speedup vs baseline: 1.1239x; 1.1239x over previous
//
#include <hip/hip_runtime.h>

// DHPM fused forward v9 (MI355X / gfx950).
// vs v7/v8: 256-thread blocks (4 waves = 2 pt-groups x 2 trig-groups, 32
// pts/block) with launch_bounds(256,4): VGPR cap 128 (fits ~120 demand, no
// spill) AND 4 blocks/CU -> 4 independent barrier domains hide each other's
// stalls. Single barrier per nt with BIDIRECTIONAL exchange (g0 sends wc;
// g1 sends Ydx,Ydy; both read post-barrier; no RMW tail). f-net: per-owned-
// tile sequential bF loads to cap registers.

#define HID 200
#define NT 13
#define KT 7
#define BLDK 232           // f16 row stride of W tiles (464 B = 29 granules, odd)
#define WCHUNK 8192
#define NTH 256
#define ELD 36             // exchange row stride (floats; 9 granules, odd)

#define OFF_WU 0           // [13][16][232] f16, 8 KB padded per nt
#define OFF_WV 106496
#define OFF_WF 212992
#define OFF_CU 319488      // [200][8] f32 {ax,ay,at,b0,-ax^2,-ay^2,0,0}
#define OFF_CV 325888
#define OFF_CF 332288      // [200][16] f32 {Wf0 row(12), bf0, pad}

typedef _Float16 f16;
typedef _Float16 f16x2 __attribute__((ext_vector_type(2)));
typedef _Float16 f16x8 __attribute__((ext_vector_type(8)));
typedef float f32x4 __attribute__((ext_vector_type(4)));

#define GLDS16(gp, lp) __builtin_amdgcn_global_load_lds( \
    (const __attribute__((address_space(1))) void*)(gp), \
    (__attribute__((address_space(3))) void*)(lp), 16, 0, 0)

__global__ __launch_bounds__(256) void dhpm_prep(
    const float* __restrict__ Wu1, const float* __restrict__ Wv1, const float* __restrict__ Wf1,
    const float* __restrict__ Wu0, const float* __restrict__ bu0,
    const float* __restrict__ Wv0, const float* __restrict__ bv0,
    const float* __restrict__ Wf0, const float* __restrict__ bf0,
    char* __restrict__ ws)
{
    int id = blockIdx.x * blockDim.x + threadIdx.x;
    const int nW = 3 * NT * 16 * 116;   // 72384
    if (id < nW) {
        const int net = id / (NT*16*116);
        int e = id - net * (NT*16*116);
        const int nt  = e / (16*116);  e -= nt * (16*116);
        const int row = e / 116;
        const int k2  = e - row * 116;
        const int j   = nt*16 + row;
        const int k   = k2*2;
        const float* W = (net == 0) ? Wu1 : (net == 1) ? Wv1 : Wf1;
        f16x2 v; v[0] = (f16)0.f; v[1] = (f16)0.f;
        if (j < HID) {
            if (k     < HID) v[0] = (f16)W[j*HID + k];
            if (k + 1 < HID) v[1] = (f16)W[j*HID + k + 1];
        }
        *(f16x2*)(ws + net*106496 + nt*WCHUNK + row*464 + k2*4) = v;
        return;
    }
    id -= nW;
    if (id < 400) {
        const int net = id / HID;
        const int r   = id - net*HID;
        const float* W0 = net ? Wv0 : Wu0;
        const float* b0 = net ? bv0 : bu0;
        const float ax = W0[r*3+0], ay = W0[r*3+1], at = W0[r*3+2];
        float4 c0, c1;
        c0.x = ax; c0.y = ay; c0.z = at; c0.w = b0[r];
        c1.x = -ax*ax; c1.y = -ay*ay; c1.z = 0.f; c1.w = 0.f;
        char* p = ws + (net ? OFF_CV : OFF_CU) + r*32;
        *(float4*)(p)      = c0;
        *(float4*)(p + 16) = c1;
        return;
    }
    id -= 400;
    if (id < HID) {
        const int i = id;
        float4 c0, c1, c2, c3;
        c0.x = Wf0[i*12+0];  c0.y = Wf0[i*12+1];  c0.z = Wf0[i*12+2];  c0.w = Wf0[i*12+3];
        c1.x = Wf0[i*12+4];  c1.y = Wf0[i*12+5];  c1.z = Wf0[i*12+6];  c1.w = Wf0[i*12+7];
        c2.x = Wf0[i*12+8];  c2.y = Wf0[i*12+9];  c2.z = Wf0[i*12+10]; c2.w = Wf0[i*12+11];
        c3.x = bf0[i]; c3.y = 0.f; c3.z = 0.f; c3.w = 0.f;
        char* p = ws + OFF_CF + i*64;
        *(float4*)(p)      = c0;
        *(float4*)(p + 16) = c1;
        *(float4*)(p + 32) = c2;
        *(float4*)(p + 48) = c3;
    }
}

__device__ __forceinline__ f32x4 mfma16(f16x8 a, f16x8 b, f32x4 c) {
    return __builtin_amdgcn_mfma_f32_16x16x32_f16(a, b, c, 0, 0, 0);
}

// g0: acc = {Yval, Yxx, Yyy}; partials {val, xx, yy}.
// g1: acc = {Ydx, Ydy, Ydt};  partials {dx, dy, dt}.
__device__ __forceinline__ void run_net(
    const float* __restrict__ inp, const char* __restrict__ ws,
    const int wOff, const int cstOff,
    const float* __restrict__ b1, const float* __restrict__ W2, const float b2s,
    const int cV, const int cXX, const int cYY,
    const int cX, const int cY, const int cT,
    char* __restrict__ Bb0, char* __restrict__ Bb1,
    float* __restrict__ exch, float* __restrict__ res,
    const int gp0, const int lane, const int w, const int q, const int g,
    const int jl, const int klo)
{
    const char* src = ws + wOff;

    // stage nt=0 -> Bb0 (256 thr x 2 x 16B = 8 KB), overlaps A'-build
    GLDS16(src + w*1024 + lane*16, Bb0 + w*1024);
    GLDS16(src + 4096 + w*1024 + lane*16, Bb0 + 4096 + w*1024);

    // ---- A' fragments: 3 channels x 7 kt = 84 VGPR ----
    f16x8 aP[3][KT];
    {
        const float4* cst = (const float4*)(ws + cstOff);   // [200][2] float4
        const int pt = gp0 + q*16 + jl;
        const float x = inp[pt*3+0], y = inp[pt*3+1], tt = inp[pt*3+2];
        #pragma unroll
        for (int kt = 0; kt < KT; ++kt) {
            f16x8 f0, f1, f2;
            #pragma unroll
            for (int e = 0; e < 8; ++e) {
                const int i = kt*32 + klo*8 + e;
                const int ic = (i < HID) ? i : 0;   // pad-k cols of B are 0
                const float4 c = cst[ic*2];
                const float z = fmaf(c.x, x, fmaf(c.y, y, fmaf(c.z, tt, c.w)));
                if (g == 0) {
                    const float4 c2 = cst[ic*2+1];  // {-ax^2, -ay^2, -, -}
                    const float s = __sinf(z);
                    f0[e] = (f16)s;
                    f1[e] = (f16)(s * c2.x);
                    f2[e] = (f16)(s * c2.y);
                } else {
                    const float cv = __cosf(z);
                    f0[e] = (f16)(cv * c.x);
                    f1[e] = (f16)(cv * c.y);
                    f2[e] = (f16)(cv * c.z);
                }
            }
            aP[0][kt] = f0; aP[1][kt] = f1; aP[2][kt] = f2;
        }
    }

    float p0a[4] = {0,0,0,0}, p1a[4] = {0,0,0,0}, p2a[4] = {0,0,0,0};

    __syncthreads();   // Bb0 landed (vmcnt drain); prior-phase LDS dead

    for (int nt = 0; nt < NT; ++nt) {
        const char* Bcur = (nt & 1) ? Bb1 : Bb0;
        char*       Bnxt = (nt & 1) ? Bb0 : Bb1;
        if (nt + 1 < NT) {
            const char* s2 = src + (nt+1)*WCHUNK;
            GLDS16(s2 + w*1024 + lane*16, Bnxt + w*1024);
            GLDS16(s2 + 4096 + w*1024 + lane*16, Bnxt + 4096 + w*1024);
        }

        // early-issue epilogue scalars (latency hidden under MFMAs)
        const int j = nt*16 + jl;
        float bj = 0.f, wj = 0.f;
        if (g == 0 && j < HID) { bj = b1[j]; wj = W2[j]; }

        f32x4 acc0 = {0,0,0,0}, acc1 = {0,0,0,0}, acc2 = {0,0,0,0};
        const f16* BH = (const f16*)Bcur;
        #pragma unroll
        for (int kt = 0; kt < KT; ++kt) {
            const f16x8 b = *(const f16x8*)&BH[jl*BLDK + kt*32 + klo*8];
            acc0 = mfma16(aP[0][kt], b, acc0);
            acc1 = mfma16(aP[1][kt], b, acc1);
            acc2 = mfma16(aP[2][kt], b, acc2);
        }

        const int pcol = q*16 + klo*4;
        float* EX = exch + (nt & 1) * (3*16*ELD);
        float ws4[4];
        if (g == 0) {
            f32x4 wc4;
            #pragma unroll
            for (int r = 0; r < 4; ++r) {
                float s1, c1;
                __sincosf(acc0[r] + bj, &s1, &c1);
                wc4[r] = wj * c1;
                ws4[r] = wj * s1;
                p0a[r] += ws4[r];                          // val
                p1a[r] = fmaf(wc4[r], acc1[r], p1a[r]);    // +wc*Yxx
                p2a[r] = fmaf(wc4[r], acc2[r], p2a[r]);    // +wc*Yyy
            }
            *(f32x4*)&EX[0*16*ELD + jl*ELD + pcol] = wc4;
        } else {
            *(f32x4*)&EX[1*16*ELD + jl*ELD + pcol] = acc0;   // Ydx
            *(f32x4*)&EX[2*16*ELD + jl*ELD + pcol] = acc1;   // Ydy
        }
        __syncthreads();   // exch visible; Bnxt landed; Bcur reads done
        if (g == 0) {
            const f32x4 ydx = *(const f32x4*)&EX[1*16*ELD + jl*ELD + pcol];
            const f32x4 ydy = *(const f32x4*)&EX[2*16*ELD + jl*ELD + pcol];
            #pragma unroll
            for (int r = 0; r < 4; ++r) {
                p1a[r] = fmaf(-ws4[r]*ydx[r], ydx[r], p1a[r]);   // -wsn*Ydx^2
                p2a[r] = fmaf(-ws4[r]*ydy[r], ydy[r], p2a[r]);   // -wsn*Ydy^2
            }
        } else {
            const f32x4 wc4 = *(const f32x4*)&EX[0*16*ELD + jl*ELD + pcol];
            #pragma unroll
            for (int r = 0; r < 4; ++r) {
                p0a[r] = fmaf(wc4[r], acc0[r], p0a[r]);   // dx
                p1a[r] = fmaf(wc4[r], acc1[r], p1a[r]);   // dy
                p2a[r] = fmaf(wc4[r], acc2[r], p2a[r]);   // dt
            }
        }
    }

    // butterfly over the 16 j-lanes
    #pragma unroll
    for (int d = 1; d < 16; d <<= 1)
        #pragma unroll
        for (int r = 0; r < 4; ++r) {
            p0a[r] += __shfl_xor(p0a[r], d);
            p1a[r] += __shfl_xor(p1a[r], d);
            p2a[r] += __shfl_xor(p2a[r], d);
        }
    if (jl == 0) {
        const int p0 = q*16 + klo*4;
        f32x4 v;
        if (g == 0) {
            #pragma unroll
            for (int r = 0; r < 4; ++r) v[r] = p0a[r] + b2s;
            *(f32x4*)&res[cV*ELD + p0] = v;
            #pragma unroll
            for (int r = 0; r < 4; ++r) v[r] = p1a[r];
            *(f32x4*)&res[cXX*ELD + p0] = v;
            #pragma unroll
            for (int r = 0; r < 4; ++r) v[r] = p2a[r];
            *(f32x4*)&res[cYY*ELD + p0] = v;
        } else {
            #pragma unroll
            for (int r = 0; r < 4; ++r) v[r] = p0a[r];
            *(f32x4*)&res[cX*ELD + p0] = v;
            #pragma unroll
            for (int r = 0; r < 4; ++r) v[r] = p1a[r];
            *(f32x4*)&res[cY*ELD + p0] = v;
            #pragma unroll
            for (int r = 0; r < 4; ++r) v[r] = p2a[r];
            *(f32x4*)&res[cT*ELD + p0] = v;
        }
    }
}

__global__ __launch_bounds__(NTH, 4) void dhpm_main(
    const float* __restrict__ inp, const char* __restrict__ ws,
    const float* __restrict__ bu1, const float* __restrict__ Wu2, const float* __restrict__ bu2,
    const float* __restrict__ bv1, const float* __restrict__ Wv2, const float* __restrict__ bv2,
    const float* __restrict__ bf1, const float* __restrict__ Wf2, const float* __restrict__ bf2,
    float* __restrict__ out, const int Np)
{
    __shared__ __align__(16) char LDS[33280];
    char*  Bb0  = LDS;                        // 8 KB
    char*  Bb1  = LDS + 8192;                 // 8 KB
    float* exch = (float*)(LDS + 16384);      // 6*16*36*4 = 13824 B
    f16*   Af   = (f16*)LDS;                  // f-net: [32][232] f16 = 14848 B (aliases Bb)
    float* res  = (float*)(LDS + 30208);      // [14][36] f32 = 2016 B
    float* pfb  = (float*)(LDS + 32224);      // [4][2][32] f32 = 1024 B

    const int t = threadIdx.x;
    const int lane = t & 63;
    const int w = __builtin_amdgcn_readfirstlane(t >> 6);
    const int q = w & 1, g = w >> 1;
    const int jl = lane & 15, klo = lane >> 4;
    const int gp0 = blockIdx.x * 32;

    run_net(inp, ws, OFF_WU, OFF_CU, bu1, Wu2, bu2[0], 0, 5, 7, 4, 6, 2,
            Bb0, Bb1, exch, res, gp0, lane, w, q, g, jl, klo);
    run_net(inp, ws, OFF_WV, OFF_CV, bv1, Wv2, bv2[0], 1, 9, 11, 8, 10, 3,
            Bb0, Bb1, exch, res, gp0, lane, w, q, g, jl, klo);

    __syncthreads();   // res cols 0..11 final; Bb/exch region free

    // ======================= f-net =======================
    // waves 0,1 build A_f (16 pts each); each wave owns nt = w + 4*ont.
    if (w < 2) {
        const int p = w*16 + jl;
        float fv[12];
        #pragma unroll
        for (int k = 0; k < 12; ++k) fv[k] = res[k*ELD + p];
        const float4* cf = (const float4*)(ws + OFF_CF);
        #pragma unroll
        for (int kt = 0; kt < KT; ++kt) {
            f16x8 f;
            #pragma unroll
            for (int e = 0; e < 8; ++e) {
                const int i = kt*32 + klo*8 + e;
                const int ic = (i < HID) ? i : 0;
                const float4 c0 = cf[ic*4+0];
                const float4 c1 = cf[ic*4+1];
                const float4 c2 = cf[ic*4+2];
                const float4 c3 = cf[ic*4+3];
                float z = c3.x;
                z = fmaf(c0.x, fv[0], z);  z = fmaf(c0.y, fv[1], z);
                z = fmaf(c0.z, fv[2], z);  z = fmaf(c0.w, fv[3], z);
                z = fmaf(c1.x, fv[4], z);  z = fmaf(c1.y, fv[5], z);
                z = fmaf(c1.z, fv[6], z);  z = fmaf(c1.w, fv[7], z);
                z = fmaf(c2.x, fv[8], z);  z = fmaf(c2.y, fv[9], z);
                z = fmaf(c2.z, fv[10], z); z = fmaf(c2.w, fv[11], z);
                f[e] = (f16)__sinf(z);
            }
            *(f16x8*)((char*)Af + p*464 + kt*64 + klo*16) = f;
        }
    }
    __syncthreads();   // A_f complete

    f16x8 aF[2][KT];
    #pragma unroll
    for (int mt = 0; mt < 2; ++mt) {
        const int row = mt*16 + jl;
        #pragma unroll
        for (int kt = 0; kt < KT; ++kt)
            aF[mt][kt] = *(const f16x8*)((const char*)Af + row*464 + kt*64 + klo*16);
    }

    float pf0[2][4] = {{0,0,0,0},{0,0,0,0}};
    float pf1[2][4] = {{0,0,0,0},{0,0,0,0}};
    const int nown = (w == 0) ? 4 : 3;
    for (int ont = 0; ont < nown; ++ont) {
        const int nt = w + ont*4;
        f16x8 bF[KT];
        #pragma unroll
        for (int kt = 0; kt < KT; ++kt)
            bF[kt] = *(const f16x8*)(ws + OFF_WF + nt*WCHUNK
                                      + jl*464 + kt*64 + klo*16);
        f32x4 accF[2] = {{0,0,0,0},{0,0,0,0}};
        #pragma unroll
        for (int kt = 0; kt < KT; ++kt) {
            accF[0] = mfma16(aF[0][kt], bF[kt], accF[0]);
            accF[1] = mfma16(aF[1][kt], bF[kt], accF[1]);
        }
        const int j = nt*16 + jl;
        const float bj = (j < HID) ? bf1[j] : 0.f;
        const float wa = (j < HID) ? Wf2[j] : 0.f;
        const float wb = (j < HID) ? Wf2[HID + j] : 0.f;
        #pragma unroll
        for (int mt = 0; mt < 2; ++mt)
            #pragma unroll
            for (int r = 0; r < 4; ++r) {
                const float h = __sinf(accF[mt][r] + bj);
                pf0[mt][r] = fmaf(wa, h, pf0[mt][r]);
                pf1[mt][r] = fmaf(wb, h, pf1[mt][r]);
            }
    }

    #pragma unroll
    for (int d = 1; d < 16; d <<= 1)
        #pragma unroll
        for (int mt = 0; mt < 2; ++mt)
            #pragma unroll
            for (int r = 0; r < 4; ++r) {
                pf0[mt][r] += __shfl_xor(pf0[mt][r], d);
                pf1[mt][r] += __shfl_xor(pf1[mt][r], d);
            }
    if (jl == 0) {
        #pragma unroll
        for (int mt = 0; mt < 2; ++mt) {
            const int p0 = mt*16 + klo*4;
            f32x4 v0, v1;
            #pragma unroll
            for (int r = 0; r < 4; ++r) { v0[r] = pf0[mt][r]; v1[r] = pf1[mt][r]; }
            *(f32x4*)&pfb[w*64 + 0*32 + p0] = v0;
            *(f32x4*)&pfb[w*64 + 1*32 + p0] = v1;
        }
    }
    __syncthreads();
    if (t < 64) {
        const int pt = t & 31, ch = t >> 5;
        float s = bf2[ch];
        #pragma unroll
        for (int ww = 0; ww < 4; ++ww) s += pfb[ww*64 + ch*32 + pt];
        res[(12 + ch)*ELD + pt] = s;
    }
    __syncthreads();

    // coalesced final store
    for (int e = t; e < 14*32; e += NTH) {
        const int c = e >> 5, p = e & 31;
        out[(size_t)c*Np + gp0 + p] = res[c*ELD + p];
    }
}

extern "C" void kernel_launch(void* const* d_in, const int* in_sizes, int n_in,
                              void* d_out, int out_size, void* d_ws, size_t ws_size,
                              hipStream_t stream) {
    const float* inp = (const float*)d_in[0];
    const float* Wu0 = (const float*)d_in[1];  const float* bu0 = (const float*)d_in[2];
    const float* Wu1 = (const float*)d_in[3];  const float* bu1 = (const float*)d_in[4];
    const float* Wu2 = (const float*)d_in[5];  const float* bu2 = (const float*)d_in[6];
    const float* Wv0 = (const float*)d_in[7];  const float* bv0 = (const float*)d_in[8];
    const float* Wv1 = (const float*)d_in[9];  const float* bv1 = (const float*)d_in[10];
    const float* Wv2 = (const float*)d_in[11]; const float* bv2 = (const float*)d_in[12];
    const float* Wf0 = (const float*)d_in[13]; const float* bf0 = (const float*)d_in[14];
    const float* Wf1 = (const float*)d_in[15]; const float* bf1 = (const float*)d_in[16];
    const float* Wf2 = (const float*)d_in[17]; const float* bf2 = (const float*)d_in[18];
    float* out = (float*)d_out;
    char* ws = (char*)d_ws;   // ~345 KB used

    const int Np = in_sizes[0] / 3;  // 262144

    const int nTot = 3*NT*16*116 + 400 + HID;  // 72984
    dhpm_prep<<<(nTot + 255) / 256, 256, 0, stream>>>(
        Wu1, Wv1, Wf1, Wu0, bu0, Wv0, bv0, Wf0, bf0, ws);
    dhpm_main<<<Np / 32, NTH, 0, stream>>>(
        inp, ws, bu1, Wu2, bu2, bv1, Wv2, bv2, bf1, Wf2, bf2, out, Np);
}